// Round 1
// baseline (590.363 us; speedup 1.0000x reference)
//
#include <hip/hip_runtime.h>

static constexpr int NN = 100000;   // nodes
static constexpr int NE = 1600000;  // edges (without self-loops)

// ---------------- degree / normalization ----------------

__global__ void k_deg_init(float* __restrict__ deg) {
    int i = blockIdx.x * blockDim.x + threadIdx.x;
    if (i < NN) deg[i] = 1.0f;  // self-loop contributes 1
}

__global__ void k_deg_accum(const int* __restrict__ dst, float* __restrict__ deg) {
    int e = blockIdx.x * blockDim.x + threadIdx.x;
    if (e < NE) atomicAdd(&deg[dst[e]], 1.0f);
}

__global__ void k_rsqrt(float* __restrict__ deg) {
    int i = blockIdx.x * blockDim.x + threadIdx.x;
    if (i < NN) deg[i] = rsqrtf(deg[i]);
}

// ---------------- per-layer kernels ----------------

// Projection p = in @ W; also initializes agg with the self-loop message
// (norm for self-loop = dinv[i]*dinv[i]).
template <int FIN, int FOUT>
__global__ void k_proj(const float* __restrict__ in, const float* __restrict__ W,
                       const float* __restrict__ dinv,
                       float* __restrict__ p, float* __restrict__ agg) {
    __shared__ float Ws[FIN * FOUT];
    const int tid = threadIdx.x;
    for (int i = tid; i < FIN * FOUT; i += blockDim.x) Ws[i] = W[i];
    __syncthreads();
    constexpr int NPB = 256 / FOUT;  // nodes per block
    const int node = blockIdx.x * NPB + tid / FOUT;
    const int f = tid % FOUT;
    if (node >= NN) return;
    const float* row = in + (size_t)node * FIN;
    float acc = 0.f;
#pragma unroll
    for (int k = 0; k < FIN; ++k) acc += row[k] * Ws[k * FOUT + f];
    p[(size_t)node * FOUT + f] = acc;
    const float di = dinv[node];
    agg[(size_t)node * FOUT + f] = acc * di * di;
}

// One thread per (edge, feature): msg = p[src][f]*dinv[src]*dinv[dst] -> atomicAdd agg[dst][f]
template <int F>
__global__ void k_edge(const int* __restrict__ src, const int* __restrict__ dst,
                       const float* __restrict__ dinv, const float* __restrict__ p,
                       float* __restrict__ agg) {
    const unsigned tid = blockIdx.x * blockDim.x + threadIdx.x;
    if (tid >= (unsigned)NE * F) return;
    const unsigned e = tid / F;
    const unsigned f = tid % F;
    const int s = src[e];
    const int d = dst[e];
    const float v = p[(unsigned)s * F + f] * dinv[s] * dinv[d];
    atomicAdd(&agg[(unsigned)d * F + f], v);
}

template <int F>
__global__ void k_bias_tanh(float* __restrict__ agg, const float* __restrict__ b) {
    const unsigned tid = blockIdx.x * blockDim.x + threadIdx.x;
    if (tid >= (unsigned)NN * F) return;
    agg[tid] = tanhf(agg[tid] + b[tid % F]);
}

// Final classifier: out = in @ W + b
template <int FIN, int FOUT>
__global__ void k_matmul_bias(const float* __restrict__ in, const float* __restrict__ W,
                              const float* __restrict__ b, float* __restrict__ out) {
    __shared__ float Ws[FIN * FOUT];
    const int tid = threadIdx.x;
    for (int i = tid; i < FIN * FOUT; i += blockDim.x) Ws[i] = W[i];
    __syncthreads();
    constexpr int NPB = 256 / FOUT;
    const int node = blockIdx.x * NPB + tid / FOUT;
    const int f = tid % FOUT;
    if (node >= NN) return;
    float acc = b[f];
#pragma unroll
    for (int k = 0; k < FIN; ++k) acc += in[(size_t)node * FIN + k] * Ws[k * FOUT + f];
    out[(size_t)node * FOUT + f] = acc;
}

// ---------------- launch ----------------

extern "C" void kernel_launch(void* const* d_in, const int* in_sizes, int n_in,
                              void* d_out, int out_size, void* d_ws, size_t ws_size,
                              hipStream_t stream) {
    const float* x  = (const float*)d_in[0];
    const int*   ei = (const int*)d_in[1];   // [2, E] — src row then dst row
    const float* W1 = (const float*)d_in[2];
    const float* b1 = (const float*)d_in[3];
    const float* W2 = (const float*)d_in[4];
    const float* b2 = (const float*)d_in[5];
    const float* W3 = (const float*)d_in[6];
    const float* b3 = (const float*)d_in[7];
    const float* Wc = (const float*)d_in[8];
    const float* bc = (const float*)d_in[9];

    const int* src = ei;
    const int* dst = ei + NE;

    // workspace layout (floats): dinv[N] | B0[N*32] | B1[N*32] | B2[N*32]  (~38.8 MB)
    float* ws   = (float*)d_ws;
    float* dinv = ws;
    float* B0   = ws + NN;
    float* B1   = B0 + (size_t)NN * 32;
    float* B2   = B1 + (size_t)NN * 32;

    float* out = (float*)d_out;            // [N,8]
    float* h3  = out + (size_t)NN * 8;     // [N,16] second tuple output; also layer-3 buffer

    const int T = 256;

    // normalization: deg (incl self-loop) -> dinv = rsqrt(deg)
    k_deg_init<<<(NN + T - 1) / T, T, 0, stream>>>(dinv);
    k_deg_accum<<<(NE + T - 1) / T, T, 0, stream>>>(dst, dinv);
    k_rsqrt<<<(NN + T - 1) / T, T, 0, stream>>>(dinv);

    // Layer 1: x(32) -> B1(32)
    k_proj<32, 32><<<(NN * 32 + T - 1) / T, T, 0, stream>>>(x, W1, dinv, B0, B1);
    k_edge<32><<<(int)(((unsigned)NE * 32 + T - 1) / T), T, 0, stream>>>(src, dst, dinv, B0, B1);
    k_bias_tanh<32><<<(NN * 32 + T - 1) / T, T, 0, stream>>>(B1, b1);

    // Layer 2: B1(32) -> B2(32)
    k_proj<32, 32><<<(NN * 32 + T - 1) / T, T, 0, stream>>>(B1, W2, dinv, B0, B2);
    k_edge<32><<<(int)(((unsigned)NE * 32 + T - 1) / T), T, 0, stream>>>(src, dst, dinv, B0, B2);
    k_bias_tanh<32><<<(NN * 32 + T - 1) / T, T, 0, stream>>>(B2, b2);

    // Layer 3: B2(32) -> h3(16) living directly in d_out's second region
    k_proj<32, 16><<<(NN * 16 + T - 1) / T, T, 0, stream>>>(B2, W3, dinv, B0, h3);
    k_edge<16><<<(int)(((unsigned)NE * 16 + T - 1) / T), T, 0, stream>>>(src, dst, dinv, B0, h3);
    k_bias_tanh<16><<<(NN * 16 + T - 1) / T, T, 0, stream>>>(h3, b3);

    // classifier: h3(16) -> out(8)
    k_matmul_bias<16, 8><<<(NN * 8 + T - 1) / T, T, 0, stream>>>(h3, Wc, bc, out);
}

// Round 2
// 420.517 us; speedup vs baseline: 1.4039x; 1.4039x over previous
//
#include <hip/hip_runtime.h>

static constexpr int NN = 100000;   // nodes
static constexpr int NE = 1600000;  // edges (without self-loops)

static constexpr int SCAN_T = 256;       // threads per scan block
static constexpr int SCAN_E = 1024;      // elements per scan block (4/thread)
static constexpr int NBLK = (NN + SCAN_E - 1) / SCAN_E;  // 98

// ---------------- degree / CSR build ----------------

__global__ void k_zero_deg(int* __restrict__ deg) {
    int i = blockIdx.x * blockDim.x + threadIdx.x;
    if (i < NN) deg[i] = 0;
}

__global__ void k_deg_count(const int* __restrict__ dst, int* __restrict__ deg) {
    int e = blockIdx.x * blockDim.x + threadIdx.x;
    if (e < NE) atomicAdd(&deg[dst[e]], 1);
}

__global__ void k_dinv(const int* __restrict__ deg, float* __restrict__ dinv) {
    int i = blockIdx.x * blockDim.x + threadIdx.x;
    if (i < NN) dinv[i] = rsqrtf((float)deg[i] + 1.0f);  // +1 self-loop
}

// scan phase 1: per-block sums (1024 elems / block)
__global__ void k_scan1(const int* __restrict__ deg, int* __restrict__ bsum) {
    __shared__ int s[SCAN_T];
    const int t = threadIdx.x;
    const int base = blockIdx.x * SCAN_E + t * 4;
    int v = 0;
#pragma unroll
    for (int j = 0; j < 4; ++j) {
        int i = base + j;
        if (i < NN) v += deg[i];
    }
    s[t] = v;
    __syncthreads();
    for (int off = SCAN_T / 2; off > 0; off >>= 1) {
        if (t < off) s[t] += s[t + off];
        __syncthreads();
    }
    if (t == 0) bsum[blockIdx.x] = s[0];
}

// scan phase 2: exclusive scan of block sums (NBLK <= 128), single block
__global__ void k_scan2(int* __restrict__ bsum) {
    __shared__ int s[128];
    const int t = threadIdx.x;  // 128 threads
    const int v = (t < NBLK) ? bsum[t] : 0;
    s[t] = v;
    __syncthreads();
    for (int off = 1; off < 128; off <<= 1) {
        int add = (t >= off) ? s[t - off] : 0;
        __syncthreads();
        s[t] += add;
        __syncthreads();
    }
    if (t < NBLK) bsum[t] = s[t] - v;  // exclusive
}

// scan phase 3: per-element exclusive offsets; also init scatter cursor
__global__ void k_scan3(const int* __restrict__ deg, const int* __restrict__ bsum,
                        int* __restrict__ offs, int* __restrict__ cursor) {
    __shared__ int s[SCAN_T];
    const int t = threadIdx.x;
    const int base = blockIdx.x * SCAN_E + t * 4;
    int v[4];
    int tsum = 0;
#pragma unroll
    for (int j = 0; j < 4; ++j) {
        int i = base + j;
        v[j] = (i < NN) ? deg[i] : 0;
        tsum += v[j];
    }
    s[t] = tsum;
    __syncthreads();
    for (int off = 1; off < SCAN_T; off <<= 1) {
        int add = (t >= off) ? s[t - off] : 0;
        __syncthreads();
        s[t] += add;
        __syncthreads();
    }
    int run = bsum[blockIdx.x] + (s[t] - tsum);  // block base + thread-exclusive
#pragma unroll
    for (int j = 0; j < 4; ++j) {
        int i = base + j;
        if (i < NN) {
            offs[i] = run;
            cursor[i] = run;
        }
        run += v[j];
    }
}

__global__ void k_scatter(const int* __restrict__ src, const int* __restrict__ dst,
                          int* __restrict__ cursor, int* __restrict__ csr_src) {
    int e = blockIdx.x * blockDim.x + threadIdx.x;
    if (e < NE) {
        int d = dst[e];
        int slot = atomicAdd(&cursor[d], 1);
        csr_src[slot] = src[e];
    }
}

// ---------------- per-layer kernels ----------------

// p' = (in @ W) * dinv[node]   (dinv[src] factor pre-folded)
template <int FIN, int FOUT>
__global__ void k_proj(const float* __restrict__ in, const float* __restrict__ W,
                       const float* __restrict__ dinv, float* __restrict__ p) {
    constexpr int NPB = 256 / FOUT;
    __shared__ float Ws[FIN * FOUT];
    __shared__ float rows[NPB][FIN];
    const int tid = threadIdx.x;
    for (int i = tid; i < FIN * FOUT; i += 256) Ws[i] = W[i];
    const int nl = tid / FOUT;
    const int f = tid % FOUT;
    const int node = blockIdx.x * NPB + nl;
    if (node < NN) {
        for (int k = f; k < FIN; k += FOUT) rows[nl][k] = in[(size_t)node * FIN + k];
    }
    __syncthreads();
    if (node >= NN) return;
    float acc = 0.f;
#pragma unroll
    for (int k = 0; k < FIN; ++k) acc += rows[nl][k] * Ws[k * FOUT + f];
    p[(size_t)node * FOUT + f] = acc * dinv[node];
}

// out[d] = tanh( dinv[d] * ( p'[d] + sum_{s in N(d)} p'[s] ) + b )
template <int F>
__global__ void k_aggregate(const float* __restrict__ p, const int* __restrict__ offs,
                            const int* __restrict__ deg, const int* __restrict__ csr_src,
                            const float* __restrict__ dinv, const float* __restrict__ b,
                            float* __restrict__ outp) {
    constexpr int NPB = 256 / F;
    const int tid = threadIdx.x;
    const int node = blockIdx.x * NPB + tid / F;
    const int f = tid % F;
    if (node >= NN) return;
    float acc = p[(size_t)node * F + f];  // self-loop (dinv[node] already folded)
    const int start = offs[node];
    const int cnt = deg[node];
    for (int kk = 0; kk < cnt; kk += F) {
        const int myk = kk + f;
        int s_l = 0;
        if (myk < cnt) s_l = csr_src[start + myk];  // coalesced batch load
        const int lim = (cnt - kk < F) ? (cnt - kk) : F;
        for (int j = 0; j < lim; ++j) {
            const int s = __shfl(s_l, j, F);  // broadcast within node's lane group
            acc += p[(size_t)s * F + f];
        }
    }
    acc = dinv[node] * acc + b[f];
    outp[(size_t)node * F + f] = tanhf(acc);
}

// classifier: out = in @ W + b
template <int FIN, int FOUT>
__global__ void k_matmul_bias(const float* __restrict__ in, const float* __restrict__ W,
                              const float* __restrict__ b, float* __restrict__ out) {
    constexpr int NPB = 256 / FOUT;
    __shared__ float Ws[FIN * FOUT];
    __shared__ float rows[NPB][FIN];
    const int tid = threadIdx.x;
    for (int i = tid; i < FIN * FOUT; i += 256) Ws[i] = W[i];
    const int nl = tid / FOUT;
    const int f = tid % FOUT;
    const int node = blockIdx.x * NPB + nl;
    if (node < NN) {
        for (int k = f; k < FIN; k += FOUT) rows[nl][k] = in[(size_t)node * FIN + k];
    }
    __syncthreads();
    if (node >= NN) return;
    float acc = b[f];
#pragma unroll
    for (int k = 0; k < FIN; ++k) acc += rows[nl][k] * Ws[k * FOUT + f];
    out[(size_t)node * FOUT + f] = acc;
}

// ---------------- launch ----------------

extern "C" void kernel_launch(void* const* d_in, const int* in_sizes, int n_in,
                              void* d_out, int out_size, void* d_ws, size_t ws_size,
                              hipStream_t stream) {
    const float* x  = (const float*)d_in[0];
    const int*   ei = (const int*)d_in[1];   // [2, E]: src row, dst row
    const float* W1 = (const float*)d_in[2];
    const float* b1 = (const float*)d_in[3];
    const float* W2 = (const float*)d_in[4];
    const float* b2 = (const float*)d_in[5];
    const float* W3 = (const float*)d_in[6];
    const float* b3 = (const float*)d_in[7];
    const float* Wc = (const float*)d_in[8];
    const float* bc = (const float*)d_in[9];

    const int* src = ei;
    const int* dst = ei + NE;

    // ws layout: deg[N] | offs[N] | cursor[N] | bsum[128] | dinv[N] | csr_src[E] | B0[N*32] | B1[N*32]
    // total ~33.6 MB
    int*   deg     = (int*)d_ws;
    int*   offs    = deg + NN;
    int*   cursor  = offs + NN;
    int*   bsum    = cursor + NN;
    float* dinv    = (float*)(bsum + 128);
    int*   csr_src = (int*)(dinv + NN);
    float* B0      = (float*)(csr_src + NE);      // p' buffer [N,32]
    float* B1      = B0 + (size_t)NN * 32;        // h buffer  [N,32]

    float* out = (float*)d_out;            // [N,8]
    float* h3  = out + (size_t)NN * 8;     // [N,16] (second tuple output)

    const int T = 256;

    // ---- CSR build + normalization ----
    k_zero_deg<<<(NN + T - 1) / T, T, 0, stream>>>(deg);
    k_deg_count<<<(NE + T - 1) / T, T, 0, stream>>>(dst, deg);
    k_dinv<<<(NN + T - 1) / T, T, 0, stream>>>(deg, dinv);
    k_scan1<<<NBLK, SCAN_T, 0, stream>>>(deg, bsum);
    k_scan2<<<1, 128, 0, stream>>>(bsum);
    k_scan3<<<NBLK, SCAN_T, 0, stream>>>(deg, bsum, offs, cursor);
    k_scatter<<<(NE + T - 1) / T, T, 0, stream>>>(src, dst, cursor, csr_src);

    // ---- Layer 1: x(32) -> B1(32) ----
    k_proj<32, 32><<<(NN + 7) / 8, T, 0, stream>>>(x, W1, dinv, B0);
    k_aggregate<32><<<(NN + 7) / 8, T, 0, stream>>>(B0, offs, deg, csr_src, dinv, b1, B1);

    // ---- Layer 2: B1(32) -> B1(32) ----
    k_proj<32, 32><<<(NN + 7) / 8, T, 0, stream>>>(B1, W2, dinv, B0);
    k_aggregate<32><<<(NN + 7) / 8, T, 0, stream>>>(B0, offs, deg, csr_src, dinv, b2, B1);

    // ---- Layer 3: B1(32) -> h3(16) ----
    k_proj<32, 16><<<(NN + 15) / 16, T, 0, stream>>>(B1, W3, dinv, B0);
    k_aggregate<16><<<(NN + 15) / 16, T, 0, stream>>>(B0, offs, deg, csr_src, dinv, b3, h3);

    // ---- classifier: h3(16) -> out(8) ----
    k_matmul_bias<16, 8><<<(NN + 31) / 32, T, 0, stream>>>(h3, Wc, bc, out);
}

// Round 3
// 261.726 us; speedup vs baseline: 2.2556x; 1.6067x over previous
//
#include <hip/hip_runtime.h>

static constexpr int NN = 100000;   // nodes
static constexpr int NE = 1600000;  // edges (without self-loops)

static constexpr int BSH   = 9;                        // 512 nodes / bucket
static constexpr int NDB   = 1 << BSH;                 // 512
static constexpr int NBUCK = (NN + NDB - 1) / NDB;     // 196
static constexpr int BCAP  = 9216;                     // mean 8192, sigma ~90 -> +11 sigma
static constexpr int TILE  = 4096;                     // edges per bin block
static constexpr int BIN_T = 256;
static constexpr int EPT   = TILE / BIN_T;             // 16

static_assert(NBUCK <= 256, "bucket count must fit one block");

// ---------------- binned CSR build ----------------

__global__ void k_init_cur(int* __restrict__ gcur) {
    const int t = threadIdx.x;
    if (t < NBUCK) gcur[t] = t * BCAP;
}

// Pass 1: bin edges into 196 coarse buckets; packed rec = (src<<9)|dstLow.
// Per-block contiguous runs reserved via one atomic per (block,bucket) -> writes
// land line-clustered (no 64B-per-4B amplification).
__global__ __launch_bounds__(BIN_T) void k_bin(const int* __restrict__ src,
                                               const int* __restrict__ dst,
                                               int* __restrict__ gcur,
                                               unsigned* __restrict__ bkt) {
    __shared__ int hist[NBUCK];
    __shared__ int cur[NBUCK];
    const int t = threadIdx.x;
    const int e0 = blockIdx.x * TILE;
    const int n = (NE - e0 < TILE) ? (NE - e0) : TILE;
    for (int i = t; i < NBUCK; i += BIN_T) hist[i] = 0;
    __syncthreads();
    unsigned rec[EPT];
    int bb[EPT];
#pragma unroll
    for (int j = 0; j < EPT; ++j) {
        const int i = t + j * BIN_T;
        bb[j] = -1;
        if (i < n) {
            const int s = src[e0 + i];
            const int d = dst[e0 + i];
            bb[j] = d >> BSH;
            rec[j] = ((unsigned)s << BSH) | (unsigned)(d & (NDB - 1));
            atomicAdd(&hist[bb[j]], 1);
        }
    }
    __syncthreads();
    for (int i = t; i < NBUCK; i += BIN_T) {
        const int c = hist[i];
        cur[i] = (c > 0) ? atomicAdd(&gcur[i], c) : 0;  // global run base
    }
    __syncthreads();
#pragma unroll
    for (int j = 0; j < EPT; ++j) {
        if (bb[j] >= 0) {
            const int pos = atomicAdd(&cur[bb[j]], 1);
            bkt[pos] = rec[j];
        }
    }
}

// exclusive scan of bucket counts -> global CSR base per bucket
__global__ void k_bucket_scan(const int* __restrict__ gcur, int* __restrict__ bbase) {
    __shared__ int sc[256];
    __shared__ int c0[256];
    const int t = threadIdx.x;
    const int c = (t < NBUCK) ? (gcur[t] - t * BCAP) : 0;
    sc[t] = c;
    c0[t] = c;
    __syncthreads();
    for (int off = 1; off < 256; off <<= 1) {
        const int a = (t >= off) ? sc[t - off] : 0;
        __syncthreads();
        sc[t] += a;
        __syncthreads();
    }
    if (t < NBUCK) bbase[t] = sc[t] - c0[t];
}

// Pass 2: per-bucket LDS counting sort -> exact CSR; also emits deg/offs/dinv.
__global__ __launch_bounds__(256) void k_build(const unsigned* __restrict__ bkt,
                                               const int* __restrict__ gcur,
                                               const int* __restrict__ bbase,
                                               int* __restrict__ csr_src,
                                               int* __restrict__ deg,
                                               int* __restrict__ offs,
                                               float* __restrict__ dinv) {
    __shared__ unsigned buf[BCAP];   // 36 KB
    __shared__ int hist[NDB];
    __shared__ int sc[NDB];
    __shared__ int cur[NDB];
    const int b = blockIdx.x;
    const int t = threadIdx.x;
    const int n0 = b << BSH;
    const int nn = (NN - n0 < NDB) ? (NN - n0) : NDB;
    int cnt = gcur[b] - b * BCAP;
    if (cnt > BCAP) cnt = BCAP;
    for (int i = t; i < NDB; i += 256) hist[i] = 0;
    __syncthreads();
    for (int i = t; i < cnt; i += 256) {
        const unsigned r = bkt[(size_t)b * BCAP + i];
        buf[i] = r;
        atomicAdd(&hist[r & (NDB - 1)], 1);
    }
    __syncthreads();
    // inclusive scan of hist (512 elems, 256 threads, Hillis-Steele)
    sc[t] = hist[t];
    sc[t + 256] = hist[t + 256];
    __syncthreads();
    for (int off = 1; off < NDB; off <<= 1) {
        const int a0 = (t >= off) ? sc[t - off] : 0;
        const int a1 = (t + 256 >= off) ? sc[t + 256 - off] : 0;
        __syncthreads();
        sc[t] += a0;
        sc[t + 256] += a1;
        __syncthreads();
    }
    const int base = bbase[b];
    for (int i = t; i < NDB; i += 256) {
        const int e = sc[i] - hist[i];  // exclusive
        cur[i] = e;
        if (i < nn) {
            const int node = n0 + i;
            deg[node] = hist[i];
            offs[node] = base + e;
            dinv[node] = rsqrtf((float)hist[i] + 1.0f);  // +1 self-loop
        }
    }
    __syncthreads();
    for (int i = t; i < cnt; i += 256) {
        const unsigned r = buf[i];
        const int pos = atomicAdd(&cur[r & (NDB - 1)], 1);
        csr_src[base + pos] = (int)(r >> BSH);  // scattered only within block's 36 KB run
    }
}

// ---------------- per-layer kernels ----------------

// p' = (in @ W) * dinv[node]   (dinv[src] factor pre-folded)
template <int FIN, int FOUT>
__global__ void k_proj(const float* __restrict__ in, const float* __restrict__ W,
                       const float* __restrict__ dinv, float* __restrict__ p) {
    constexpr int NPB = 256 / FOUT;
    __shared__ float Ws[FIN * FOUT];
    __shared__ float rows[NPB][FIN];
    const int tid = threadIdx.x;
    for (int i = tid; i < FIN * FOUT; i += 256) Ws[i] = W[i];
    const int nl = tid / FOUT;
    const int f = tid % FOUT;
    const int node = blockIdx.x * NPB + nl;
    if (node < NN) {
        for (int k = f; k < FIN; k += FOUT) rows[nl][k] = in[(size_t)node * FIN + k];
    }
    __syncthreads();
    if (node >= NN) return;
    float acc = 0.f;
#pragma unroll
    for (int k = 0; k < FIN; ++k) acc += rows[nl][k] * Ws[k * FOUT + f];
    p[(size_t)node * FOUT + f] = acc * dinv[node];
}

// out[d] = tanh( dinv[d] * ( p'[d] + sum_{s in N(d)} p'[s] ) + b )
template <int F>
__global__ void k_aggregate(const float* __restrict__ p, const int* __restrict__ offs,
                            const int* __restrict__ deg, const int* __restrict__ csr_src,
                            const float* __restrict__ dinv, const float* __restrict__ b,
                            float* __restrict__ outp) {
    constexpr int NPB = 256 / F;
    const int tid = threadIdx.x;
    const int node = blockIdx.x * NPB + tid / F;
    const int f = tid % F;
    if (node >= NN) return;
    float acc = p[(size_t)node * F + f];  // self-loop (dinv[node] already folded)
    const int start = offs[node];
    const int cnt = deg[node];
    for (int kk = 0; kk < cnt; kk += F) {
        const int myk = kk + f;
        int s_l = 0;
        if (myk < cnt) s_l = csr_src[start + myk];  // coalesced batch load
        const int lim = (cnt - kk < F) ? (cnt - kk) : F;
        for (int j = 0; j < lim; ++j) {
            const int s = __shfl(s_l, j, F);  // broadcast within node's lane group
            acc += p[(size_t)s * F + f];
        }
    }
    acc = dinv[node] * acc + b[f];
    outp[(size_t)node * F + f] = tanhf(acc);
}

// classifier: out = in @ W + b
template <int FIN, int FOUT>
__global__ void k_matmul_bias(const float* __restrict__ in, const float* __restrict__ W,
                              const float* __restrict__ b, float* __restrict__ out) {
    constexpr int NPB = 256 / FOUT;
    __shared__ float Ws[FIN * FOUT];
    __shared__ float rows[NPB][FIN];
    const int tid = threadIdx.x;
    for (int i = tid; i < FIN * FOUT; i += 256) Ws[i] = W[i];
    const int nl = tid / FOUT;
    const int f = tid % FOUT;
    const int node = blockIdx.x * NPB + nl;
    if (node < NN) {
        for (int k = f; k < FIN; k += FOUT) rows[nl][k] = in[(size_t)node * FIN + k];
    }
    __syncthreads();
    if (node >= NN) return;
    float acc = b[f];
#pragma unroll
    for (int k = 0; k < FIN; ++k) acc += rows[nl][k] * Ws[k * FOUT + f];
    out[(size_t)node * FOUT + f] = acc;
}

// ---------------- launch ----------------

extern "C" void kernel_launch(void* const* d_in, const int* in_sizes, int n_in,
                              void* d_out, int out_size, void* d_ws, size_t ws_size,
                              hipStream_t stream) {
    const float* x  = (const float*)d_in[0];
    const int*   ei = (const int*)d_in[1];   // [2, E]: src row, dst row
    const float* W1 = (const float*)d_in[2];
    const float* b1 = (const float*)d_in[3];
    const float* W2 = (const float*)d_in[4];
    const float* b2 = (const float*)d_in[5];
    const float* W3 = (const float*)d_in[6];
    const float* b3 = (const float*)d_in[7];
    const float* Wc = (const float*)d_in[8];
    const float* bc = (const float*)d_in[9];

    const int* src = ei;
    const int* dst = ei + NE;

    // ws layout: gcur[256] | bbase[256] | deg[N] | offs[N] | dinv[N] | csr_src[E] | B0[N*32] | B1[N*32]
    // bkt (7.2 MB) aliases B0 (12.8 MB) — bkt is dead before the first k_proj writes B0.
    int*   gcur    = (int*)d_ws;
    int*   bbase   = gcur + 256;
    int*   deg     = bbase + 256;
    int*   offs    = deg + NN;
    float* dinv    = (float*)(offs + NN);
    int*   csr_src = (int*)(dinv + NN);
    float* B0      = (float*)(csr_src + NE);      // p' buffer [N,32]
    float* B1      = B0 + (size_t)NN * 32;        // h buffer  [N,32]
    unsigned* bkt  = (unsigned*)B0;

    float* out = (float*)d_out;            // [N,8]
    float* h3  = out + (size_t)NN * 8;     // [N,16] (second tuple output)

    const int T = 256;

    // ---- CSR build (binned counting sort; also emits deg/offs/dinv) ----
    k_init_cur<<<1, T, 0, stream>>>(gcur);
    k_bin<<<(NE + TILE - 1) / TILE, BIN_T, 0, stream>>>(src, dst, gcur, bkt);
    k_bucket_scan<<<1, T, 0, stream>>>(gcur, bbase);
    k_build<<<NBUCK, T, 0, stream>>>(bkt, gcur, bbase, csr_src, deg, offs, dinv);

    // ---- Layer 1: x(32) -> B1(32) ----
    k_proj<32, 32><<<(NN + 7) / 8, T, 0, stream>>>(x, W1, dinv, B0);
    k_aggregate<32><<<(NN + 7) / 8, T, 0, stream>>>(B0, offs, deg, csr_src, dinv, b1, B1);

    // ---- Layer 2: B1(32) -> B1(32) ----
    k_proj<32, 32><<<(NN + 7) / 8, T, 0, stream>>>(B1, W2, dinv, B0);
    k_aggregate<32><<<(NN + 7) / 8, T, 0, stream>>>(B0, offs, deg, csr_src, dinv, b2, B1);

    // ---- Layer 3: B1(32) -> h3(16) ----
    k_proj<32, 16><<<(NN + 15) / 16, T, 0, stream>>>(B1, W3, dinv, B0);
    k_aggregate<16><<<(NN + 15) / 16, T, 0, stream>>>(B0, offs, deg, csr_src, dinv, b3, h3);

    // ---- classifier: h3(16) -> out(8) ----
    k_matmul_bias<16, 8><<<(NN + 31) / 32, T, 0, stream>>>(h3, Wc, bc, out);
}

// Round 4
// 194.257 us; speedup vs baseline: 3.0391x; 1.3473x over previous
//
#include <hip/hip_runtime.h>

static constexpr int NN = 100000;   // nodes
static constexpr int NE = 1600000;  // edges (without self-loops)

static constexpr int BSH   = 9;                        // 512 nodes / bucket
static constexpr int NDB   = 1 << BSH;                 // 512
static constexpr int NBUCK = (NN + NDB - 1) / NDB;     // 196
static constexpr int BCAP  = 9216;                     // mean 8192, sigma ~90 -> +11 sigma
static constexpr int TILE  = 4096;                     // edges per bin block
static constexpr int BIN_T = 256;
static constexpr int EPT   = TILE / BIN_T;             // 16

static_assert(NBUCK <= 256, "bucket count must fit one block");

// ---------------- binned CSR build ----------------

__global__ void k_init_cur(int* __restrict__ gcur) {
    const int t = threadIdx.x;
    if (t < NBUCK) gcur[t] = t * BCAP;
}

// Pass 1: bin edges into 196 coarse buckets; packed rec = (src<<9)|dstLow.
__global__ __launch_bounds__(BIN_T) void k_bin(const int* __restrict__ src,
                                               const int* __restrict__ dst,
                                               int* __restrict__ gcur,
                                               unsigned* __restrict__ bkt) {
    __shared__ int hist[NBUCK];
    __shared__ int cur[NBUCK];
    const int t = threadIdx.x;
    const int e0 = blockIdx.x * TILE;
    const int n = (NE - e0 < TILE) ? (NE - e0) : TILE;
    for (int i = t; i < NBUCK; i += BIN_T) hist[i] = 0;
    __syncthreads();
    unsigned rec[EPT];
    int bb[EPT];
#pragma unroll
    for (int j = 0; j < EPT; ++j) {
        const int i = t + j * BIN_T;
        bb[j] = -1;
        if (i < n) {
            const int s = src[e0 + i];
            const int d = dst[e0 + i];
            bb[j] = d >> BSH;
            rec[j] = ((unsigned)s << BSH) | (unsigned)(d & (NDB - 1));
            atomicAdd(&hist[bb[j]], 1);
        }
    }
    __syncthreads();
    for (int i = t; i < NBUCK; i += BIN_T) {
        const int c = hist[i];
        cur[i] = (c > 0) ? atomicAdd(&gcur[i], c) : 0;  // global run base
    }
    __syncthreads();
#pragma unroll
    for (int j = 0; j < EPT; ++j) {
        if (bb[j] >= 0) {
            const int pos = atomicAdd(&cur[bb[j]], 1);
            bkt[pos] = rec[j];
        }
    }
}

// exclusive scan of bucket counts -> global CSR base per bucket
__global__ void k_bucket_scan(const int* __restrict__ gcur, int* __restrict__ bbase) {
    __shared__ int sc[256];
    __shared__ int c0[256];
    const int t = threadIdx.x;
    const int c = (t < NBUCK) ? (gcur[t] - t * BCAP) : 0;
    sc[t] = c;
    c0[t] = c;
    __syncthreads();
    for (int off = 1; off < 256; off <<= 1) {
        const int a = (t >= off) ? sc[t - off] : 0;
        __syncthreads();
        sc[t] += a;
        __syncthreads();
    }
    if (t < NBUCK) bbase[t] = sc[t] - c0[t];
}

// Pass 2: per-bucket LDS counting sort -> exact CSR; also emits deg/offs/dinv.
__global__ __launch_bounds__(256) void k_build(const unsigned* __restrict__ bkt,
                                               const int* __restrict__ gcur,
                                               const int* __restrict__ bbase,
                                               int* __restrict__ csr_src,
                                               int* __restrict__ deg,
                                               int* __restrict__ offs,
                                               float* __restrict__ dinv) {
    __shared__ unsigned buf[BCAP];   // 36 KB
    __shared__ int hist[NDB];
    __shared__ int sc[NDB];
    __shared__ int cur[NDB];
    const int b = blockIdx.x;
    const int t = threadIdx.x;
    const int n0 = b << BSH;
    const int nn = (NN - n0 < NDB) ? (NN - n0) : NDB;
    int cnt = gcur[b] - b * BCAP;
    if (cnt > BCAP) cnt = BCAP;
    for (int i = t; i < NDB; i += 256) hist[i] = 0;
    __syncthreads();
    for (int i = t; i < cnt; i += 256) {
        const unsigned r = bkt[(size_t)b * BCAP + i];
        buf[i] = r;
        atomicAdd(&hist[r & (NDB - 1)], 1);
    }
    __syncthreads();
    // inclusive scan of hist (512 elems, 256 threads, Hillis-Steele)
    sc[t] = hist[t];
    sc[t + 256] = hist[t + 256];
    __syncthreads();
    for (int off = 1; off < NDB; off <<= 1) {
        const int a0 = (t >= off) ? sc[t - off] : 0;
        const int a1 = (t + 256 >= off) ? sc[t + 256 - off] : 0;
        __syncthreads();
        sc[t] += a0;
        sc[t + 256] += a1;
        __syncthreads();
    }
    const int base = bbase[b];
    for (int i = t; i < NDB; i += 256) {
        const int e = sc[i] - hist[i];  // exclusive
        cur[i] = e;
        if (i < nn) {
            const int node = n0 + i;
            deg[node] = hist[i];
            offs[node] = base + e;
            dinv[node] = rsqrtf((float)hist[i] + 1.0f);  // +1 self-loop
        }
    }
    __syncthreads();
    for (int i = t; i < cnt; i += 256) {
        const unsigned r = buf[i];
        const int pos = atomicAdd(&cur[r & (NDB - 1)], 1);
        csr_src[base + pos] = (int)(r >> BSH);
    }
}

// ---------------- per-layer kernels ----------------

// p' = (in @ W) * dinv[node]   (dinv[src] factor pre-folded)
template <int FIN, int FOUT>
__global__ void k_proj(const float* __restrict__ in, const float* __restrict__ W,
                       const float* __restrict__ dinv, float* __restrict__ p) {
    constexpr int NPB = 256 / FOUT;
    __shared__ float Ws[FIN * FOUT];
    __shared__ float rows[NPB][FIN];
    const int tid = threadIdx.x;
    for (int i = tid; i < FIN * FOUT; i += 256) Ws[i] = W[i];
    const int nl = tid / FOUT;
    const int f = tid % FOUT;
    const int node = blockIdx.x * NPB + nl;
    if (node < NN) {
        for (int k = f; k < FIN; k += FOUT) rows[nl][k] = in[(size_t)node * FIN + k];
    }
    __syncthreads();
    if (node >= NN) return;
    float acc = 0.f;
#pragma unroll
    for (int k = 0; k < FIN; ++k) acc += rows[nl][k] * Ws[k * FOUT + f];
    p[(size_t)node * FOUT + f] = acc * dinv[node];
}

// out[d] = tanh( dinv[d] * ( p'[d] + sum_{s in N(d)} p'[s] ) + b )
// Neighbor loop unrolled 16/8/4/1-wide so gather loads issue in parallel
// (latency chain ~deg -> ~2-3 steps).
template <int F>
__global__ void k_aggregate(const float* __restrict__ p, const int* __restrict__ offs,
                            const int* __restrict__ deg, const int* __restrict__ csr_src,
                            const float* __restrict__ dinv, const float* __restrict__ b,
                            float* __restrict__ outp) {
    constexpr int NPB = 256 / F;
    const int tid = threadIdx.x;
    const int node = blockIdx.x * NPB + tid / F;
    const int f = tid % F;
    if (node >= NN) return;
    float acc = p[(size_t)node * F + f];  // self-loop (dinv[node] already folded)
    const int start = offs[node];
    const int cnt = deg[node];
    for (int kk = 0; kk < cnt; kk += F) {
        const int myk = kk + f;
        int s_l = 0;
        if (myk < cnt) s_l = csr_src[start + myk];  // coalesced batch load
        const int lim = (cnt - kk < F) ? (cnt - kk) : F;
        int j = 0;
        for (; j + 16 <= lim; j += 16) {
            float v[16];
#pragma unroll
            for (int u = 0; u < 16; ++u) {
                const int s = __shfl(s_l, j + u, F);
                v[u] = p[(size_t)s * F + f];   // 16 independent loads in flight
            }
            float t0 = 0.f, t1 = 0.f;
#pragma unroll
            for (int u = 0; u < 8; ++u) { t0 += v[u]; t1 += v[u + 8]; }
            acc += t0 + t1;
        }
        for (; j + 8 <= lim; j += 8) {
            float v[8];
#pragma unroll
            for (int u = 0; u < 8; ++u) {
                const int s = __shfl(s_l, j + u, F);
                v[u] = p[(size_t)s * F + f];
            }
            acc += ((v[0] + v[1]) + (v[2] + v[3])) + ((v[4] + v[5]) + (v[6] + v[7]));
        }
        for (; j + 4 <= lim; j += 4) {
            float v[4];
#pragma unroll
            for (int u = 0; u < 4; ++u) {
                const int s = __shfl(s_l, j + u, F);
                v[u] = p[(size_t)s * F + f];
            }
            acc += (v[0] + v[1]) + (v[2] + v[3]);
        }
        for (; j < lim; ++j) {
            const int s = __shfl(s_l, j, F);
            acc += p[(size_t)s * F + f];
        }
    }
    acc = dinv[node] * acc + b[f];
    outp[(size_t)node * F + f] = tanhf(acc);
}

// classifier: out = in @ W + b
template <int FIN, int FOUT>
__global__ void k_matmul_bias(const float* __restrict__ in, const float* __restrict__ W,
                              const float* __restrict__ b, float* __restrict__ out) {
    constexpr int NPB = 256 / FOUT;
    __shared__ float Ws[FIN * FOUT];
    __shared__ float rows[NPB][FIN];
    const int tid = threadIdx.x;
    for (int i = tid; i < FIN * FOUT; i += 256) Ws[i] = W[i];
    const int nl = tid / FOUT;
    const int f = tid % FOUT;
    const int node = blockIdx.x * NPB + nl;
    if (node < NN) {
        for (int k = f; k < FIN; k += FOUT) rows[nl][k] = in[(size_t)node * FIN + k];
    }
    __syncthreads();
    if (node >= NN) return;
    float acc = b[f];
#pragma unroll
    for (int k = 0; k < FIN; ++k) acc += rows[nl][k] * Ws[k * FOUT + f];
    out[(size_t)node * FOUT + f] = acc;
}

// ---------------- launch ----------------

extern "C" void kernel_launch(void* const* d_in, const int* in_sizes, int n_in,
                              void* d_out, int out_size, void* d_ws, size_t ws_size,
                              hipStream_t stream) {
    const float* x  = (const float*)d_in[0];
    const int*   ei = (const int*)d_in[1];   // [2, E]: src row, dst row
    const float* W1 = (const float*)d_in[2];
    const float* b1 = (const float*)d_in[3];
    const float* W2 = (const float*)d_in[4];
    const float* b2 = (const float*)d_in[5];
    const float* W3 = (const float*)d_in[6];
    const float* b3 = (const float*)d_in[7];
    const float* Wc = (const float*)d_in[8];
    const float* bc = (const float*)d_in[9];

    const int* src = ei;
    const int* dst = ei + NE;

    // ws layout: gcur[256] | bbase[256] | deg[N] | offs[N] | dinv[N] | csr_src[E] | B0[N*32] | B1[N*32]
    // bkt (7.2 MB) aliases B0 (12.8 MB) — bkt is dead before the first k_proj writes B0.
    int*   gcur    = (int*)d_ws;
    int*   bbase   = gcur + 256;
    int*   deg     = bbase + 256;
    int*   offs    = deg + NN;
    float* dinv    = (float*)(offs + NN);
    int*   csr_src = (int*)(dinv + NN);
    float* B0      = (float*)(csr_src + NE);      // p' buffer [N,32]
    float* B1      = B0 + (size_t)NN * 32;        // h buffer  [N,32]
    unsigned* bkt  = (unsigned*)B0;

    float* out = (float*)d_out;            // [N,8]
    float* h3  = out + (size_t)NN * 8;     // [N,16] (second tuple output)

    const int T = 256;

    // ---- CSR build (binned counting sort; also emits deg/offs/dinv) ----
    k_init_cur<<<1, T, 0, stream>>>(gcur);
    k_bin<<<(NE + TILE - 1) / TILE, BIN_T, 0, stream>>>(src, dst, gcur, bkt);
    k_bucket_scan<<<1, T, 0, stream>>>(gcur, bbase);
    k_build<<<NBUCK, T, 0, stream>>>(bkt, gcur, bbase, csr_src, deg, offs, dinv);

    // ---- Layer 1: x(32) -> B1(32) ----
    k_proj<32, 32><<<(NN + 7) / 8, T, 0, stream>>>(x, W1, dinv, B0);
    k_aggregate<32><<<(NN + 7) / 8, T, 0, stream>>>(B0, offs, deg, csr_src, dinv, b1, B1);

    // ---- Layer 2: B1(32) -> B1(32) ----
    k_proj<32, 32><<<(NN + 7) / 8, T, 0, stream>>>(B1, W2, dinv, B0);
    k_aggregate<32><<<(NN + 7) / 8, T, 0, stream>>>(B0, offs, deg, csr_src, dinv, b2, B1);

    // ---- Layer 3: B1(32) -> h3(16) ----
    k_proj<32, 16><<<(NN + 15) / 16, T, 0, stream>>>(B1, W3, dinv, B0);
    k_aggregate<16><<<(NN + 15) / 16, T, 0, stream>>>(B0, offs, deg, csr_src, dinv, b3, h3);

    // ---- classifier: h3(16) -> out(8) ----
    k_matmul_bias<16, 8><<<(NN + 31) / 32, T, 0, stream>>>(h3, Wc, bc, out);
}